// Round 1
// baseline (98.681 us; speedup 1.0000x reference)
//
#include <hip/hip_runtime.h>
#include <math.h>

// DSS layer: y[h,l] = D[h]*u[h,l] + sum_{m<=l} K[h,m] * u[h,l-m]
// K[h,m] = Re( sum_n c_{h,n} * z_{h,n}^m )
// z = exp(step*lambda);  c = (W/lambda) * conj(s) / (|s|^2 + EPS);
// s = sum_{l<L} z^l = (1 - z^L)/(1 - z)   (argmax of Re(P) is l=0 since Re(lambda) ~ -0.5)

static constexpr int kH = 1024;
static constexpr int kL = 2048;
static constexpr int kN = 32;
static constexpr int kChunk = 32;
static constexpr int kNChunk = kL / kChunk;  // 64
static constexpr double kEps = 1e-7;

// ws layout: per (h,n) 8 floats: z_r, z_i, c_r, c_i, zC_r, zC_i, pad, pad
__global__ void dss_setup_kernel(const float* __restrict__ W,
                                 const float* __restrict__ Lambda_ri,
                                 const float* __restrict__ log_step,
                                 float* __restrict__ zc) {
    int idx = blockIdx.x * blockDim.x + threadIdx.x;  // h*kN + n
    if (idx >= kH * kN) return;
    int h = idx / kN;
    int n = idx % kN;

    double step = exp((double)log_step[h]);
    double lr = (double)Lambda_ri[2 * n + 0];
    double li = (double)Lambda_ri[2 * n + 1];
    double wr = (double)W[(h * kN + n) * 2 + 0];
    double wi = (double)W[(h * kN + n) * 2 + 1];

    double ar = step * lr;  // Re(step*lambda), ~ -0.5*step < 0
    double ai = step * li;

    // z = exp(ar + i*ai)
    double er = exp(ar);
    double zr = er * cos(ai);
    double zi = er * sin(ai);

    // z^L = exp(L*(ar + i*ai))
    double eL = exp(ar * (double)kL);
    double thL = ai * (double)kL;
    double zLr = eL * cos(thL);
    double zLi = eL * sin(thL);

    // s = (1 - z^L) / (1 - z)
    double nr = 1.0 - zLr, ni = -zLi;
    double dr = 1.0 - zr,  di = -zi;
    double dd = dr * dr + di * di;
    double sr = (nr * dr + ni * di) / dd;
    double si = (ni * dr - nr * di) / dd;

    // q = w / lambda
    double ll = lr * lr + li * li;
    double qr = (wr * lr + wi * li) / ll;
    double qi = (wi * lr - wr * li) / ll;

    // c = q * conj(s) / (|s|^2 + EPS)
    double ss = sr * sr + si * si + kEps;
    double cr = (qr * sr + qi * si) / ss;
    double ci = (qi * sr - qr * si) / ss;

    // z^kChunk for the carry combine
    double eC = exp(ar * (double)kChunk);
    double thC = ai * (double)kChunk;
    double zCr = eC * cos(thC);
    double zCi = eC * sin(thC);

    float* o = zc + idx * 8;
    o[0] = (float)zr;  o[1] = (float)zi;
    o[2] = (float)cr;  o[3] = (float)ci;
    o[4] = (float)zCr; o[5] = (float)zCi;
    o[6] = 0.f;        o[7] = 0.f;
}

// One 64-thread block per channel h. Thread t owns chunk t (kChunk elements),
// holding all kN mode states in registers.
__launch_bounds__(64, 1)
__global__ void dss_scan_kernel(const float* __restrict__ u,
                                const float* __restrict__ zc,
                                const float* __restrict__ Dv,
                                float* __restrict__ y) {
    // u staged padded (+1 float per 32) -> conflict-free strided reads.
    __shared__ float u_s[kL + kL / 32];          // 2112 floats
    __shared__ float eR[kNChunk][kN + 1];        // 64 x 33 (padded)
    __shared__ float eI[kNChunk][kN + 1];

    const int h = blockIdx.x;
    const int t = threadIdx.x;  // chunk id, 0..63

    const float* uh = u + (size_t)h * kL;
    for (int i = t; i < kL; i += 64) {
        u_s[i + (i >> 5)] = uh[i];
    }

    // Per-mode constants (uniform across block -> compiler may scalarize).
    const float* zch = zc + (size_t)h * kN * 8;
    float z_r[kN], z_i[kN], c_r[kN], c_i[kN];
#pragma unroll
    for (int n = 0; n < kN; ++n) {
        z_r[n] = zch[n * 8 + 0];
        z_i[n] = zch[n * 8 + 1];
        c_r[n] = zch[n * 8 + 2];
        c_i[n] = zch[n * 8 + 3];
    }
    __syncthreads();

    // ---- Phase 1: zero-carry scan of own chunk -> end state e_j per mode ----
    float x_r[kN], x_i[kN];
#pragma unroll
    for (int n = 0; n < kN; ++n) { x_r[n] = 0.f; x_i[n] = 0.f; }

    const int base = t * kChunk;
    for (int k = 0; k < kChunk; ++k) {
        const int i = base + k;
        const float uv = u_s[i + (i >> 5)];
#pragma unroll
        for (int n = 0; n < kN; ++n) {
            const float tr = z_i[n] * x_r[n];
            x_r[n] = fmaf(z_r[n], x_r[n], fmaf(-z_i[n], x_i[n], uv));
            x_i[n] = fmaf(z_r[n], x_i[n], tr);
        }
    }
#pragma unroll
    for (int n = 0; n < kN; ++n) { eR[t][n] = x_r[n]; eI[t][n] = x_i[n]; }
    __syncthreads();

    // ---- Phase 2: sequential carry combine per mode (threads 0..31) ----
    if (t < kN) {
        const int n = t;
        const float zCr = zch[n * 8 + 4];
        const float zCi = zch[n * 8 + 5];
        float Er = 0.f, Ei = 0.f;
        for (int j = 0; j < kNChunk; ++j) {
            const float ejr = eR[j][n];
            const float eji = eI[j][n];
            eR[j][n] = Er;  // carry-in for chunk j = scan end of chunk j-1
            eI[j][n] = Ei;
            const float nr2 = fmaf(zCr, Er, fmaf(-zCi, Ei, ejr));
            const float ni2 = fmaf(zCr, Ei, fmaf(zCi, Er, eji));
            Er = nr2; Ei = ni2;
        }
    }
    __syncthreads();

    // ---- Phase 3: rescan with carry-in, accumulate output ----
    const float Dh = Dv[h];
#pragma unroll
    for (int n = 0; n < kN; ++n) { x_r[n] = eR[t][n]; x_i[n] = eI[t][n]; }

    for (int k = 0; k < kChunk; ++k) {
        const int i = base + k;
        const float uv = u_s[i + (i >> 5)];
        float acc = Dh * uv;
#pragma unroll
        for (int n = 0; n < kN; ++n) {
            const float tr = z_i[n] * x_r[n];
            x_r[n] = fmaf(z_r[n], x_r[n], fmaf(-z_i[n], x_i[n], uv));
            x_i[n] = fmaf(z_r[n], x_i[n], tr);
            acc = fmaf(c_r[n], x_r[n], acc);
            acc = fmaf(-c_i[n], x_i[n], acc);
        }
        // stage result back into u_s (element already consumed) for coalesced store
        u_s[i + (i >> 5)] = acc;
    }
    __syncthreads();

    float* yh = y + (size_t)h * kL;
    for (int i = t; i < kL; i += 64) {
        yh[i] = u_s[i + (i >> 5)];
    }
}

extern "C" void kernel_launch(void* const* d_in, const int* in_sizes, int n_in,
                              void* d_out, int out_size, void* d_ws, size_t ws_size,
                              hipStream_t stream) {
    const float* u        = (const float*)d_in[0];  // (H, L)
    const float* W        = (const float*)d_in[1];  // (H, N, 2)
    const float* Lam      = (const float*)d_in[2];  // (N, 2)
    const float* log_step = (const float*)d_in[3];  // (H,)
    const float* Dv       = (const float*)d_in[4];  // (H,)
    float* y = (float*)d_out;                        // (H, L) fp32
    float* zc = (float*)d_ws;                        // H*N*8 floats = 1 MB

    dss_setup_kernel<<<(kH * kN + 255) / 256, 256, 0, stream>>>(W, Lam, log_step, zc);
    dss_scan_kernel<<<kH, 64, 0, stream>>>(u, zc, Dv, y);
}

// Round 2
// 89.722 us; speedup vs baseline: 1.0998x; 1.0998x over previous
//
#include <hip/hip_runtime.h>
#include <math.h>

// DSS layer: y[h,l] = D[h]*u[h,l] + sum_{m<=l} K[h,m] * u[h,l-m]
// K[h,m] = Re( sum_n c_{h,n} * z_{h,n}^m ),  z = exp(step*lambda)
// c = (W/lambda) * conj(s) / (|s|^2 + EPS),  s = (1 - z^L)/(1 - z)
// (softmax argmax shift is a no-op: Re(lambda) = -0.5 < 0 => argmax at l=0)

static constexpr int kH = 1024;
static constexpr int kL = 2048;
static constexpr int kN = 32;
static constexpr int kChunk = 32;      // elements per lane
static constexpr int kMpW = 16;        // modes per wave (2 waves/channel)
static constexpr float kEps = 1e-7f;

// ws layout per (h,n): 8 floats: z_r, z_i, c_r, c_i, zC_r, zC_i, pad, pad
__global__ void dss_setup_kernel(const float* __restrict__ W,
                                 const float* __restrict__ Lambda_ri,
                                 const float* __restrict__ log_step,
                                 float* __restrict__ zc) {
    int idx = blockIdx.x * blockDim.x + threadIdx.x;  // h*kN + n
    if (idx >= kH * kN) return;
    int h = idx / kN;
    int n = idx % kN;

    float step = expf(log_step[h]);
    float lr = Lambda_ri[2 * n + 0];
    float li = Lambda_ri[2 * n + 1];
    float wr = W[(h * kN + n) * 2 + 0];
    float wi = W[(h * kN + n) * 2 + 1];

    float ar = step * lr;   // ~ -0.5*step, in [-0.05, -5e-4]
    float ai = step * li;

    float ea = expf(ar);
    float sb, cb;
    sincosf(ai, &sb, &cb);
    float zr = ea * cb, zi = ea * sb;

    // 1 - z  (cancellation-safe: 1 - e^a cos b = -expm1(a)cos(b) + 2 sin^2(b/2))
    float em = expm1f(ar);
    float sh = sinf(0.5f * ai);
    float dr = fmaf(-em, cb, 2.f * sh * sh);
    float di = -ea * sb;

    // 1 - z^L  (|z^L| <= e^-1, no cancellation)
    float eL = expf(ar * (float)kL);
    float sL, cL;
    sincosf(ai * (float)kL, &sL, &cL);
    float nr = 1.f - eL * cL;
    float ni = -eL * sL;

    // s = (1 - z^L)/(1 - z)
    float dd = dr * dr + di * di;
    float id = 1.f / dd;
    float sr = (nr * dr + ni * di) * id;
    float si = (ni * dr - nr * di) * id;

    // q = w / lambda
    float ll = lr * lr + li * li;
    float il = 1.f / ll;
    float qr = (wr * lr + wi * li) * il;
    float qi = (wi * lr - wr * li) * il;

    // c = q * conj(s) / (|s|^2 + EPS)
    float ss = fmaf(sr, sr, fmaf(si, si, kEps));
    float is = 1.f / ss;
    float cr = (qr * sr + qi * si) * is;
    float ci = (qi * sr - qr * si) * is;

    // zC = z^kChunk
    float eC = expf(ar * (float)kChunk);
    float sC, cC;
    sincosf(ai * (float)kChunk, &sC, &cC);

    float* o = zc + idx * 8;
    o[0] = zr;      o[1] = zi;
    o[2] = cr;      o[3] = ci;
    o[4] = eC * cC; o[5] = eC * sC;
    o[6] = 0.f;     o[7] = 0.f;
}

// Block = 128 threads = 2 waves, one channel. Wave w owns modes [w*16, w*16+16).
// Lane t owns chunk t (32 elements). Phase 2 is an in-wave Kogge-Stone scan.
__global__ __launch_bounds__(128, 2)
void dss_scan_kernel(const float* __restrict__ u,
                     const float* __restrict__ zc,
                     const float* __restrict__ Dv,
                     float* __restrict__ y) {
    __shared__ float u_s[kL + (kL >> 5)];   // padded: conflict-free strided reads
    __shared__ float y0_s[kL + (kL >> 5)];
    __shared__ float y1_s[kL + (kL >> 5)];

    const int h = blockIdx.x;
    const int tid = threadIdx.x;
    const int wave = tid >> 6;   // 0 or 1
    const int lane = tid & 63;   // chunk id

    const float* uh = u + (size_t)h * kL;
    for (int i = tid; i < kL; i += 128) u_s[i + (i >> 5)] = uh[i];

    // This wave's 16 modes (uniform addresses -> scalar loads).
    const float* zch = zc + ((size_t)h * kN + wave * kMpW) * 8;
    float zr[kMpW], zi[kMpW], cr[kMpW], ci[kMpW];
#pragma unroll
    for (int n = 0; n < kMpW; ++n) {
        zr[n] = zch[n * 8 + 0];
        zi[n] = zch[n * 8 + 1];
        cr[n] = zch[n * 8 + 2];
        ci[n] = zch[n * 8 + 3];
    }
    __syncthreads();

    // ---- Phase 1: zero-carry scan of own chunk -> end state per mode ----
    float er[kMpW], ei[kMpW];
#pragma unroll
    for (int n = 0; n < kMpW; ++n) { er[n] = 0.f; ei[n] = 0.f; }

    const int base = lane * kChunk;
    for (int k = 0; k < kChunk; ++k) {
        const int i = base + k;
        const float uv = u_s[i + (i >> 5)];
#pragma unroll
        for (int n = 0; n < kMpW; ++n) {
            const float tr = zi[n] * er[n];
            er[n] = fmaf(zr[n], er[n], fmaf(-zi[n], ei[n], uv));
            ei[n] = fmaf(zr[n], ei[n], tr);
        }
    }

    // ---- Phase 2: exclusive weighted scan across lanes (ratio zC = z^32) ----
    // Shift by 1 (exclusive), then inclusive Kogge-Stone with squaring ratios.
#pragma unroll
    for (int n = 0; n < kMpW; ++n) {
        float vr = __shfl_up(er[n], 1);
        float vi = __shfl_up(ei[n], 1);
        er[n] = (lane >= 1) ? vr : 0.f;
        ei[n] = (lane >= 1) ? vi : 0.f;
    }
    float pr[kMpW], pi[kMpW];
#pragma unroll
    for (int n = 0; n < kMpW; ++n) { pr[n] = zch[n * 8 + 4]; pi[n] = zch[n * 8 + 5]; }

#pragma unroll
    for (int d = 1; d < 64; d <<= 1) {
#pragma unroll
        for (int n = 0; n < kMpW; ++n) {
            float vr = __shfl_up(er[n], d);
            float vi = __shfl_up(ei[n], d);
            const bool ok = (lane >= d);
            vr = ok ? vr : 0.f;
            vi = ok ? vi : 0.f;
            er[n] = fmaf(pr[n], vr, fmaf(-pi[n], vi, er[n]));
            ei[n] = fmaf(pr[n], vi, fmaf(pi[n], vr, ei[n]));
        }
        if (d < 32) {
#pragma unroll
            for (int n = 0; n < kMpW; ++n) {
                const float t = fmaf(pr[n], pr[n], -pi[n] * pi[n]);
                pi[n] = 2.f * pr[n] * pi[n];
                pr[n] = t;
            }
        }
    }
    // er/ei now hold the carry-in state entering chunk `lane`.

    // ---- Phase 3: rescan with carry-in, stream partial outputs to LDS ----
    const float Dh = Dv[h];
    float* ys = wave ? y1_s : y0_s;
    for (int k = 0; k < kChunk; ++k) {
        const int i = base + k;
        const float uv = u_s[i + (i >> 5)];
        float acc = wave ? 0.f : Dh * uv;
#pragma unroll
        for (int n = 0; n < kMpW; ++n) {
            const float tr = zi[n] * er[n];
            er[n] = fmaf(zr[n], er[n], fmaf(-zi[n], ei[n], uv));
            ei[n] = fmaf(zr[n], ei[n], tr);
            acc = fmaf(cr[n], er[n], acc);
            acc = fmaf(-ci[n], ei[n], acc);
        }
        ys[i + (i >> 5)] = acc;
    }
    __syncthreads();

    float* yh = y + (size_t)h * kL;
    for (int i = tid; i < kL; i += 128) {
        yh[i] = y0_s[i + (i >> 5)] + y1_s[i + (i >> 5)];
    }
}

extern "C" void kernel_launch(void* const* d_in, const int* in_sizes, int n_in,
                              void* d_out, int out_size, void* d_ws, size_t ws_size,
                              hipStream_t stream) {
    const float* u        = (const float*)d_in[0];  // (H, L)
    const float* W        = (const float*)d_in[1];  // (H, N, 2)
    const float* Lam      = (const float*)d_in[2];  // (N, 2)
    const float* log_step = (const float*)d_in[3];  // (H,)
    const float* Dv       = (const float*)d_in[4];  // (H,)
    float* y  = (float*)d_out;                      // (H, L) fp32
    float* zc = (float*)d_ws;                       // H*N*8 floats = 1 MB

    dss_setup_kernel<<<(kH * kN + 255) / 256, 256, 0, stream>>>(W, Lam, log_step, zc);
    dss_scan_kernel<<<kH, 128, 0, stream>>>(u, zc, Dv, y);
}